// Round 8
// baseline (200.769 us; speedup 1.0000x reference)
//
#include <hip/hip_runtime.h>
#include <hip/hip_bf16.h>
#include <stdint.h>

// Problem constants (B=2, T=2048, C=1024, H=16, d=64)
#define BB 2
#define TT 2048
#define CC 1024
#define HH 16
#define DD 64
#define MM (BB*TT)   // 4096 rows

// log2(e) / sqrt(C) : folded into Q at projection time; softmax runs in exp2 domain
#define C2SCALE 0.045084220027780106f

typedef __bf16 bf16x8 __attribute__((ext_vector_type(8)));
typedef float f32x4 __attribute__((ext_vector_type(4)));

// async 16B global -> LDS (dest must be linear: wave-uniform base + lane*16)
__device__ __forceinline__ void load_lds16(const void* g, void* l) {
    __builtin_amdgcn_global_load_lds((const __attribute__((address_space(1))) uint32_t*)g,
                                     (__attribute__((address_space(3))) uint32_t*)l,
                                     16, 0, 0);
}

// ---------------------------------------------------------------------------
// x (fp32) -> bf16, vectorized 4-wide
__global__ __launch_bounds__(256)
void conv_bf16(const float* __restrict__ in, __hip_bfloat16* __restrict__ out, int n4) {
    int i = blockIdx.x * 256 + threadIdx.x;
    if (i >= n4) return;
    float4 f = reinterpret_cast<const float4*>(in)[i];
    union { __hip_bfloat16 h[4]; uint2 u; } cv;
    cv.h[0] = __float2bfloat16(f.x);
    cv.h[1] = __float2bfloat16(f.y);
    cv.h[2] = __float2bfloat16(f.z);
    cv.h[3] = __float2bfloat16(f.w);
    reinterpret_cast<uint2*>(out)[i] = cv.u;
}

// All four W (CxC fp32, row-major [k][n]) -> Wt (bf16, [n][k]); z selects matrix.
__global__ __launch_bounds__(256)
void transpose_conv4(const float* __restrict__ W0, const float* __restrict__ W1,
                     const float* __restrict__ W2, const float* __restrict__ W3,
                     __hip_bfloat16* __restrict__ out) {
    __shared__ float t[32][33];
    const int z = blockIdx.z;
    const float* W = (z == 0) ? W0 : (z == 1) ? W1 : (z == 2) ? W2 : W3;
    __hip_bfloat16* Wt = out + (size_t)z * CC * CC;
    int kt = blockIdx.x * 32, nt = blockIdx.y * 32;
    int tx = threadIdx.x & 31, ty = threadIdx.x >> 5;  // 32 x 8
#pragma unroll
    for (int r = 0; r < 32; r += 8)
        t[ty + r][tx] = W[(size_t)(kt + ty + r) * CC + nt + tx];
    __syncthreads();
#pragma unroll
    for (int r = 0; r < 32; r += 8)
        Wt[(size_t)(nt + ty + r) * CC + kt + tx] = __float2bfloat16(t[tx][ty + r]);
}

// ---------------------------------------------------------------------------
// C[M][N] = A[M][K] @ Bt[N][K]^T, bf16, MFMA 16x16x32, tile 128x128, BK=64.
// K-loop: attn-identical 2-phase double buffer — stage(0); per tile:
// __syncthreads (drains tile t's async loads + prior ds_reads); stage tile
// t+1 into the other slot; compute tile t. Epilogue is the round-3 green
// code verbatim (direct V scatter).
// MODE 1: fused QKV (N=3072): n<1024 -> Q (out0, scaled by C2SCALE),
//         <2048 -> K (out1), else V per-head transposed: out2[b][h][d][T].
// MODE 2: fp32 out0 + bias.
template <int MODE>
__global__ __launch_bounds__(256)
void gemm_bt(const __hip_bfloat16* __restrict__ A,
             const __hip_bfloat16* __restrict__ Bt,
             void* __restrict__ out0, void* __restrict__ out1, void* __restrict__ out2,
             const float* __restrict__ bias,
             int M, int N, int K) {
    __shared__ __hip_bfloat16 As[2][128 * 64];
    __shared__ __hip_bfloat16 Bs[2][128 * 64];

    const int tid = threadIdx.x;
    const int wave = tid >> 6, lane = tid & 63;
    const int lg = lane >> 4, lr = lane & 15;
    const int wm = wave >> 1, wn = wave & 1;
    const int bm0 = blockIdx.y * 128, bn0 = blockIdx.x * 128;

    // stage one K-tile (A 128x64 + B 128x64) into slot; source col pre-swizzled
    auto stage = [&](int slot, int k0) {
#pragma unroll
        for (int it = 0; it < 4; ++it) {
            int c = it * 256 + tid;
            int row = c >> 3, sub = c & 7;
            int g = sub ^ (row & 7);
            load_lds16((const char*)(A + (size_t)(bm0 + row) * K + k0) + g * 16,
                       (char*)As[slot] + c * 16);
        }
#pragma unroll
        for (int it = 0; it < 4; ++it) {
            int c = it * 256 + tid;
            int row = c >> 3, sub = c & 7;
            int g = sub ^ (row & 7);
            load_lds16((const char*)(Bt + (size_t)(bn0 + row) * K + k0) + g * 16,
                       (char*)Bs[slot] + c * 16);
        }
    };

    f32x4 acc[4][4] = {};

    auto compute = [&](int slot) {
        const char* as = (const char*)As[slot];
        const char* bs = (const char*)Bs[slot];
        bf16x8 af[2][4], bf[2][4];
#pragma unroll
        for (int kk = 0; kk < 2; ++kk) {
#pragma unroll
            for (int m = 0; m < 4; ++m) {
                int row = wm * 64 + m * 16 + lr;
                af[kk][m] = *(const bf16x8*)(as + row * 128 + (((kk * 4 + lg) ^ (row & 7)) * 16));
            }
#pragma unroll
            for (int n = 0; n < 4; ++n) {
                int row = wn * 64 + n * 16 + lr;
                bf[kk][n] = *(const bf16x8*)(bs + row * 128 + (((kk * 4 + lg) ^ (row & 7)) * 16));
            }
        }
#pragma unroll
        for (int kk = 0; kk < 2; ++kk)
#pragma unroll
            for (int m = 0; m < 4; ++m)
#pragma unroll
                for (int n = 0; n < 4; ++n)
                    acc[m][n] = __builtin_amdgcn_mfma_f32_16x16x32_bf16(af[kk][m], bf[kk][n], acc[m][n], 0, 0, 0);
    };

    const int NT = K >> 6;      // K / 64
    stage(0, 0);
    for (int t = 0; t < NT; ++t) {
        __syncthreads();                                   // tile t's loads landed
        if (t + 1 < NT) stage((t + 1) & 1, (t + 1) * 64);  // prefetch under compute
        compute(t & 1);
    }

    // epilogue (round-3 green, verbatim): C/D layout col = lane&15, row = (lane>>4)*4 + reg
#pragma unroll
    for (int m = 0; m < 4; ++m)
#pragma unroll
        for (int n = 0; n < 4; ++n) {
            int row0 = bm0 + wm * 64 + m * 16 + lg * 4;
            int colf = bn0 + wn * 64 + n * 16 + lr;
            if (MODE == 2) {
#pragma unroll
                for (int r = 0; r < 4; ++r)
                    ((float*)out0)[(size_t)(row0 + r) * N + colf] = acc[m][n][r] + bias[colf];
            } else {
                int which = colf >> 10, col = colf & 1023;
                if (which < 2) {
                    __hip_bfloat16* o = which ? (__hip_bfloat16*)out1 : (__hip_bfloat16*)out0;
                    float sc = which ? 1.0f : C2SCALE;  // Q pre-scaled for exp2-domain softmax
#pragma unroll
                    for (int r = 0; r < 4; ++r)
                        o[(size_t)(row0 + r) * 1024 + col] = __float2bfloat16(acc[m][n][r] * sc);
                } else {
                    int hh = col >> 6, dd = col & 63;
                    int bI = row0 >> 11, tt = row0 & 2047;
                    union { __hip_bfloat16 h[4]; uint2 u; } pk;
#pragma unroll
                    for (int r = 0; r < 4; ++r) pk.h[r] = __float2bfloat16(acc[m][n][r]);
                    *(uint2*)((__hip_bfloat16*)out2 + ((size_t)(bI * HH + hh) * DD + dd) * TT + tt) = pk.u;
                }
            }
        }
}

// ---------------------------------------------------------------------------
// Flash-style causal attention: 8 waves x 16 q-rows (512 threads), swapped
// QK^T softmax in exp2 domain, defer-max, double-buffered K/V staging.
// 1-D grid of 512: id = (hb&7) + 8*(qt + 16*(hb>>3)); b==1 flips qt.
__global__ __launch_bounds__(512)
void attn_kernel(const __hip_bfloat16* __restrict__ Q,
                 const __hip_bfloat16* __restrict__ K,
                 const __hip_bfloat16* __restrict__ Vt,
                 __hip_bfloat16* __restrict__ att) {
    __shared__ __hip_bfloat16 Ks[2][64 * 64];   // [kv][d], XOR-swizzled
    __shared__ __hip_bfloat16 Vs[2][64 * 64];   // [d][kv], XOR-swizzled
    __shared__ __hip_bfloat16 Pl[8][16 * 72];   // per-wave P: [q_local][kv], padded

    const int tid = threadIdx.x;
    const int wave = tid >> 6, lane = tid & 63;
    const int lg = lane >> 4, lr = lane & 15;

    // XCD-contiguous decode: all qt-blocks of one (h,b) land on one XCD
    int id = blockIdx.x;
    int rest = id >> 3;
    int qt = rest & 15;
    int hb = (id & 7) + ((rest >> 4) << 3);
    const int h = hb & 15, b = hb >> 4;
    if (b & 1) qt = 15 - qt;  // complement pairing -> balanced CUs

    const size_t baseQK = ((size_t)b * TT) * CC + (size_t)h * DD;
    const __hip_bfloat16* Vth = Vt + ((size_t)(b * HH + h)) * DD * TT;
    const int wq0 = qt * 128 + wave * 16;

    bf16x8 qf[2];
#pragma unroll
    for (int kf = 0; kf < 2; ++kf)
        qf[kf] = *(const bf16x8*)&Q[baseQK + (size_t)(wq0 + lr) * CC + kf * 32 + lg * 8];

    float m_run = -1e30f, l_run = 0.f;
    f32x4 o[4] = {};

    const int nkt = qt * 2 + 2;

    // stage one 64-kv tile (K + V^T): 512 threads x 1 chunk of 16B per matrix
    auto stage = [&](int bufi, int kv0) {
        int row = tid >> 3, sub = tid & 7;
        int g = sub ^ (row & 7);
        load_lds16((const char*)(K + baseQK + (size_t)(kv0 + row) * CC) + g * 16,
                   (char*)Ks[bufi] + tid * 16);
        load_lds16((const char*)(Vth + (size_t)row * TT + kv0) + g * 16,
                   (char*)Vs[bufi] + tid * 16);
    };

    stage(0, 0);  // prologue

    for (int kt = 0; kt < nkt; ++kt) {
        const int kv0 = kt * 64;
        __syncthreads();                      // tile kt's loads complete
        if (kt + 1 < nkt) stage((kt + 1) & 1, kv0 + 64);  // prefetch under compute
        const char* Kb = (const char*)Ks[kt & 1];
        const char* Vb = (const char*)Vs[kt & 1];

        if (kv0 > wq0 + 15) continue;  // fully-masked for this wave

        // S^T = K @ Q^T : s[nf] row = kv_local (nf*16+lg*4+r), col = q_local (lr)
        f32x4 s[4] = {};
#pragma unroll
        for (int kf = 0; kf < 2; ++kf) {
            bf16x8 kfr[4];
#pragma unroll
            for (int nf = 0; nf < 4; ++nf)
                kfr[nf] = *(const bf16x8*)(Kb + (nf * 16 + lr) * 128 + (((kf * 4 + lg) ^ (lr & 7)) * 16));
#pragma unroll
            for (int nf = 0; nf < 4; ++nf)
                s[nf] = __builtin_amdgcn_mfma_f32_16x16x32_bf16(kfr[nf], qf[kf], s[nf], 0, 0, 0);
        }

        const bool needMask = (kv0 + 63 > wq0);
        const int qg = wq0 + lr;
        float mx = -1e30f;
#pragma unroll
        for (int nf = 0; nf < 4; ++nf)
#pragma unroll
            for (int r = 0; r < 4; ++r) {
                float sv = s[nf][r];
                if (needMask) {
                    int kvg = kv0 + nf * 16 + lg * 4 + r;
                    sv = (kvg > qg) ? -1e30f : sv;
                    s[nf][r] = sv;
                }
                mx = fmaxf(mx, sv);
            }
        mx = fmaxf(mx, __shfl_xor(mx, 16, 64));
        mx = fmaxf(mx, __shfl_xor(mx, 32, 64));

        // defer-max (T13): only rescale when max grows by > 8 (exp2 domain)
        bool grow = __any(mx > m_run + 8.0f);
        float sc = 0.0f;
        if (grow) {
            float mnew = fmaxf(m_run, mx);
            sc = __builtin_amdgcn_exp2f(m_run - mnew);
            m_run = mnew;
        }
        float rsum = 0.f;
#pragma unroll
        for (int nf = 0; nf < 4; ++nf)
#pragma unroll
            for (int r = 0; r < 4; ++r) {
                float p = __builtin_amdgcn_exp2f(s[nf][r] - m_run);
                s[nf][r] = p;
                rsum += p;
            }
        rsum += __shfl_xor(rsum, 16, 64);
        rsum += __shfl_xor(rsum, 32, 64);
        if (grow) {
            l_run = l_run * sc + rsum;
#pragma unroll
            for (int r = 0; r < 4; ++r) {
                float sco = __shfl(sc, lg * 4 + r, 64);
#pragma unroll
                for (int df = 0; df < 4; ++df) o[df][r] *= sco;
            }
        } else {
            l_run += rsum;
        }

        // P^T regs -> per-wave LDS as P[q][kv] (packed b64 writes), then PV
        __hip_bfloat16* Pw = &Pl[wave][0];
#pragma unroll
        for (int nf = 0; nf < 4; ++nf) {
            union { __hip_bfloat16 h[4]; uint2 u; } pk;
#pragma unroll
            for (int r = 0; r < 4; ++r) pk.h[r] = __float2bfloat16(s[nf][r]);
            *(uint2*)&Pw[lr * 72 + nf * 16 + lg * 4] = pk.u;
        }

#pragma unroll
        for (int ks = 0; ks < 2; ++ks) {
            bf16x8 pf = *(const bf16x8*)&Pw[lr * 72 + ks * 32 + lg * 8];
            bf16x8 vf[4];
#pragma unroll
            for (int df = 0; df < 4; ++df)
                vf[df] = *(const bf16x8*)(Vb + (df * 16 + lr) * 128 + (((ks * 4 + lg) ^ (lr & 7)) * 16));
#pragma unroll
            for (int df = 0; df < 4; ++df)
                o[df] = __builtin_amdgcn_mfma_f32_16x16x32_bf16(pf, vf[df], o[df], 0, 0, 0);
        }
    }

    // normalize + store att (bf16); l broadcast into O-row layout (row = lg*4+r)
#pragma unroll
    for (int r = 0; r < 4; ++r) {
        float lo = __shfl(l_run, lg * 4 + r, 64);
        float inv = 1.0f / lo;
        int qg = wq0 + lg * 4 + r;
#pragma unroll
        for (int df = 0; df < 4; ++df)
            att[baseQK + (size_t)qg * CC + df * 16 + lr] = __float2bfloat16(o[df][r] * inv);
    }
}

// ---------------------------------------------------------------------------
extern "C" void kernel_launch(void* const* d_in, const int* in_sizes, int n_in,
                              void* d_out, int out_size, void* d_ws, size_t ws_size,
                              hipStream_t stream) {
    const float* x  = (const float*)d_in[0];
    // d_in[1] = attention_mask: no-op in the reference
    const float* Wq = (const float*)d_in[2];
    const float* Wk = (const float*)d_in[3];
    const float* Wv = (const float*)d_in[4];
    const float* Wp = (const float*)d_in[5];
    const float* bp = (const float*)d_in[6];
    float* out = (float*)d_out;

    __hip_bfloat16* ws  = (__hip_bfloat16*)d_ws;
    __hip_bfloat16* xb  = ws;                       // MM*CC
    __hip_bfloat16* wqt = xb  + (size_t)MM * CC;    // CC*CC each, contiguous (QKV concat + Wp)
    __hip_bfloat16* wpt = wqt + 3 * (size_t)CC * CC;
    __hip_bfloat16* Qb  = wpt + (size_t)CC * CC;    // MM*CC
    __hip_bfloat16* Kb  = Qb  + (size_t)MM * CC;    // MM*CC
    __hip_bfloat16* VtG = Kb  + (size_t)MM * CC;    // [B][H][D][T]
    __hip_bfloat16* att = VtG + (size_t)MM * CC;    // MM*CC

    // 1) conversions (fused weight transposes)
    conv_bf16<<<(MM * CC / 4 + 255) / 256, 256, 0, stream>>>(x, xb, MM * CC / 4);
    transpose_conv4<<<dim3(CC / 32, CC / 32, 4), 256, 0, stream>>>(Wq, Wk, Wv, Wp, wqt);

    // 2) fused QKV projection (N=3072; Q pre-scaled; V written per-head transposed)
    dim3 gq(3 * CC / 128, MM / 128);  // (24, 32)
    gemm_bt<1><<<gq, 256, 0, stream>>>(xb, wqt, Qb, Kb, VtG, nullptr, MM, 3 * CC, CC);

    // 3) causal attention (1-D grid, XCD-contiguous mapping, 512-thread blocks)
    attn_kernel<<<dim3(512), 512, 0, stream>>>(Qb, Kb, VtG, att);

    // 4) output projection + bias (fp32 out)
    dim3 gp(CC / 128, MM / 128);  // (8, 32)
    gemm_bt<2><<<gp, 256, 0, stream>>>(att, wpt, out, nullptr, nullptr, bp, MM, CC, CC);
}

// Round 9
// 196.916 us; speedup vs baseline: 1.0196x; 1.0196x over previous
//
#include <hip/hip_runtime.h>
#include <hip/hip_bf16.h>
#include <stdint.h>

// Problem constants (B=2, T=2048, C=1024, H=16, d=64)
#define BB 2
#define TT 2048
#define CC 1024
#define HH 16
#define DD 64
#define MM (BB*TT)   // 4096 rows

// log2(e) / sqrt(C) : folded into Q at projection time; softmax runs in exp2 domain
#define C2SCALE 0.045084220027780106f

typedef __bf16 bf16x8 __attribute__((ext_vector_type(8)));
typedef float f32x4 __attribute__((ext_vector_type(4)));

// async 16B global -> LDS (dest must be linear: wave-uniform base + lane*16)
__device__ __forceinline__ void load_lds16(const void* g, void* l) {
    __builtin_amdgcn_global_load_lds((const __attribute__((address_space(1))) uint32_t*)g,
                                     (__attribute__((address_space(3))) uint32_t*)l,
                                     16, 0, 0);
}

// ---------------------------------------------------------------------------
// x (fp32) -> bf16, vectorized 4-wide
__global__ __launch_bounds__(256)
void conv_bf16(const float* __restrict__ in, __hip_bfloat16* __restrict__ out, int n4) {
    int i = blockIdx.x * 256 + threadIdx.x;
    if (i >= n4) return;
    float4 f = reinterpret_cast<const float4*>(in)[i];
    union { __hip_bfloat16 h[4]; uint2 u; } cv;
    cv.h[0] = __float2bfloat16(f.x);
    cv.h[1] = __float2bfloat16(f.y);
    cv.h[2] = __float2bfloat16(f.z);
    cv.h[3] = __float2bfloat16(f.w);
    reinterpret_cast<uint2*>(out)[i] = cv.u;
}

// All four W (CxC fp32, row-major [k][n]) -> Wt (bf16, [n][k]); z selects matrix.
__global__ __launch_bounds__(256)
void transpose_conv4(const float* __restrict__ W0, const float* __restrict__ W1,
                     const float* __restrict__ W2, const float* __restrict__ W3,
                     __hip_bfloat16* __restrict__ out) {
    __shared__ float t[32][33];
    const int z = blockIdx.z;
    const float* W = (z == 0) ? W0 : (z == 1) ? W1 : (z == 2) ? W2 : W3;
    __hip_bfloat16* Wt = out + (size_t)z * CC * CC;
    int kt = blockIdx.x * 32, nt = blockIdx.y * 32;
    int tx = threadIdx.x & 31, ty = threadIdx.x >> 5;  // 32 x 8
#pragma unroll
    for (int r = 0; r < 32; r += 8)
        t[ty + r][tx] = W[(size_t)(kt + ty + r) * CC + nt + tx];
    __syncthreads();
#pragma unroll
    for (int r = 0; r < 32; r += 8)
        Wt[(size_t)(nt + ty + r) * CC + kt + tx] = __float2bfloat16(t[tx][ty + r]);
}

// ---------------------------------------------------------------------------
// C[M][N] = A[M][K] @ Bt[N][K]^T, bf16, MFMA 16x16x32.
// WAVE-PRIVATE pipeline: block tile 128x128 = 2x2 waves, each wave owns a
// private 64x64 output tile and a private dbuf LDS region (2 slots x
// (A 4KB + B 4KB)). Per K-tile (BK=32): issue 8 global_load_lds for tile
// t+1 -> s_waitcnt vmcnt(8) (per-wave FIFO; tile t landed) -> 8
// ds_read_b128 + 16 MFMA. NO __syncthreads in the K-loop: no cross-wave
// LDS visibility needed, so no cross-wave races by construction.
// LDS reads 2-way-conflict-free via chunk ^= (row>>1)&3 swizzle.
// MODE 1: fused QKV (N=3072): n<1024 -> Q (out0, scaled by C2SCALE),
//         <2048 -> K (out1), else V per-head transposed: out2[b][h][d][T].
// MODE 2: fp32 out0 + bias.
template <int MODE>
__global__ __launch_bounds__(256)
void gemm_bt(const __hip_bfloat16* __restrict__ A,
             const __hip_bfloat16* __restrict__ Bt,
             void* __restrict__ out0, void* __restrict__ out1, void* __restrict__ out2,
             const float* __restrict__ bias,
             int M, int N, int K) {
    // per-wave: [wave][slot][0..4096) = A 64x32, [4096..8192) = B 64x32
    __shared__ char lds[4][2][8192];

    const int tid = threadIdx.x;
    const int wave = tid >> 6, lane = tid & 63;
    const int lg = lane >> 4, lr = lane & 15;
    const int wm = wave >> 1, wn = wave & 1;
    const int bm0 = blockIdx.y * 128, bn0 = blockIdx.x * 128;

    const __hip_bfloat16* Aw = A + (size_t)(bm0 + wm * 64) * K;   // wave's 64 A-rows
    const __hip_bfloat16* Bw = Bt + (size_t)(bn0 + wn * 64) * K;  // wave's 64 B-rows

    // stage tile (k0) into slot: 8 global_load_lds per lane (4 A + 4 B).
    // chunk c = lane + 64*i -> row = c>>2, pos p = c&3; LDS dest = 16*c
    // (linear in lane); global chunk g = p ^ ((row>>1)&3)  [read-side XOR].
    auto stage = [&](int slot, int k0) {
        char* base = lds[wave][slot];
#pragma unroll
        for (int i = 0; i < 4; ++i) {
            int c = lane + 64 * i;
            int row = c >> 2, p = c & 3;
            int g = p ^ ((row >> 1) & 3);
            load_lds16((const char*)(Aw + (size_t)row * K + k0) + g * 16, base + c * 16);
        }
#pragma unroll
        for (int i = 0; i < 4; ++i) {
            int c = lane + 64 * i;
            int row = c >> 2, p = c & 3;
            int g = p ^ ((row >> 1) & 3);
            load_lds16((const char*)(Bw + (size_t)row * K + k0) + g * 16, base + 4096 + c * 16);
        }
    };

    f32x4 acc[4][4] = {};
    const int rchunk = lg ^ ((lr >> 1) & 3);  // row = m*16+lr -> (row>>1)&3 = (lr>>1)&3

    auto compute = [&](int slot) {
        const char* as = lds[wave][slot];
        const char* bs = as + 4096;
        bf16x8 af[4], bf[4];
#pragma unroll
        for (int m = 0; m < 4; ++m)
            af[m] = *(const bf16x8*)(as + (m * 16 + lr) * 64 + rchunk * 16);
#pragma unroll
        for (int n = 0; n < 4; ++n)
            bf[n] = *(const bf16x8*)(bs + (n * 16 + lr) * 64 + rchunk * 16);
#pragma unroll
        for (int m = 0; m < 4; ++m)
#pragma unroll
            for (int n = 0; n < 4; ++n)
                acc[m][n] = __builtin_amdgcn_mfma_f32_16x16x32_bf16(af[m], bf[n], acc[m][n], 0, 0, 0);
    };

    const int NT = K >> 5;  // K / 32
    stage(0, 0);
    __builtin_amdgcn_sched_barrier(0);  // pin FIFO: tile-0's 8 loads issue first
    for (int t = 0; t < NT; ++t) {
        if (t + 1 < NT) {
            stage((t + 1) & 1, (t + 1) * 32);
            asm volatile("s_waitcnt vmcnt(8)" ::: "memory");  // tile t landed (t+1 in flight)
        } else {
            asm volatile("s_waitcnt vmcnt(0)" ::: "memory");  // last tile
        }
        compute(t & 1);
    }

    // epilogue (green r3/r8, verbatim): C/D layout col = lane&15, row = (lane>>4)*4 + reg
#pragma unroll
    for (int m = 0; m < 4; ++m)
#pragma unroll
        for (int n = 0; n < 4; ++n) {
            int row0 = bm0 + wm * 64 + m * 16 + lg * 4;
            int colf = bn0 + wn * 64 + n * 16 + lr;
            if (MODE == 2) {
#pragma unroll
                for (int r = 0; r < 4; ++r)
                    ((float*)out0)[(size_t)(row0 + r) * N + colf] = acc[m][n][r] + bias[colf];
            } else {
                int which = colf >> 10, col = colf & 1023;
                if (which < 2) {
                    __hip_bfloat16* o = which ? (__hip_bfloat16*)out1 : (__hip_bfloat16*)out0;
                    float sc = which ? 1.0f : C2SCALE;  // Q pre-scaled for exp2-domain softmax
#pragma unroll
                    for (int r = 0; r < 4; ++r)
                        o[(size_t)(row0 + r) * 1024 + col] = __float2bfloat16(acc[m][n][r] * sc);
                } else {
                    int hh = col >> 6, dd = col & 63;
                    int bI = row0 >> 11, tt = row0 & 2047;
                    union { __hip_bfloat16 h[4]; uint2 u; } pk;
#pragma unroll
                    for (int r = 0; r < 4; ++r) pk.h[r] = __float2bfloat16(acc[m][n][r]);
                    *(uint2*)((__hip_bfloat16*)out2 + ((size_t)(bI * HH + hh) * DD + dd) * TT + tt) = pk.u;
                }
            }
        }
}

// ---------------------------------------------------------------------------
// Flash-style causal attention: 8 waves x 16 q-rows (512 threads), swapped
// QK^T softmax in exp2 domain, defer-max, double-buffered K/V staging.
// 1-D grid of 512: id = (hb&7) + 8*(qt + 16*(hb>>3)); b==1 flips qt.
__global__ __launch_bounds__(512)
void attn_kernel(const __hip_bfloat16* __restrict__ Q,
                 const __hip_bfloat16* __restrict__ K,
                 const __hip_bfloat16* __restrict__ Vt,
                 __hip_bfloat16* __restrict__ att) {
    __shared__ __hip_bfloat16 Ks[2][64 * 64];   // [kv][d], XOR-swizzled
    __shared__ __hip_bfloat16 Vs[2][64 * 64];   // [d][kv], XOR-swizzled
    __shared__ __hip_bfloat16 Pl[8][16 * 72];   // per-wave P: [q_local][kv], padded

    const int tid = threadIdx.x;
    const int wave = tid >> 6, lane = tid & 63;
    const int lg = lane >> 4, lr = lane & 15;

    // XCD-contiguous decode: all qt-blocks of one (h,b) land on one XCD
    int id = blockIdx.x;
    int rest = id >> 3;
    int qt = rest & 15;
    int hb = (id & 7) + ((rest >> 4) << 3);
    const int h = hb & 15, b = hb >> 4;
    if (b & 1) qt = 15 - qt;  // complement pairing -> balanced CUs

    const size_t baseQK = ((size_t)b * TT) * CC + (size_t)h * DD;
    const __hip_bfloat16* Vth = Vt + ((size_t)(b * HH + h)) * DD * TT;
    const int wq0 = qt * 128 + wave * 16;

    bf16x8 qf[2];
#pragma unroll
    for (int kf = 0; kf < 2; ++kf)
        qf[kf] = *(const bf16x8*)&Q[baseQK + (size_t)(wq0 + lr) * CC + kf * 32 + lg * 8];

    float m_run = -1e30f, l_run = 0.f;
    f32x4 o[4] = {};

    const int nkt = qt * 2 + 2;

    // stage one 64-kv tile (K + V^T): 512 threads x 1 chunk of 16B per matrix
    auto stage = [&](int bufi, int kv0) {
        int row = tid >> 3, sub = tid & 7;
        int g = sub ^ (row & 7);
        load_lds16((const char*)(K + baseQK + (size_t)(kv0 + row) * CC) + g * 16,
                   (char*)Ks[bufi] + tid * 16);
        load_lds16((const char*)(Vth + (size_t)row * TT + kv0) + g * 16,
                   (char*)Vs[bufi] + tid * 16);
    };

    stage(0, 0);  // prologue

    for (int kt = 0; kt < nkt; ++kt) {
        const int kv0 = kt * 64;
        __syncthreads();                      // tile kt's loads complete
        if (kt + 1 < nkt) stage((kt + 1) & 1, kv0 + 64);  // prefetch under compute
        const char* Kb = (const char*)Ks[kt & 1];
        const char* Vb = (const char*)Vs[kt & 1];

        if (kv0 > wq0 + 15) continue;  // fully-masked for this wave

        // S^T = K @ Q^T : s[nf] row = kv_local (nf*16+lg*4+r), col = q_local (lr)
        f32x4 s[4] = {};
#pragma unroll
        for (int kf = 0; kf < 2; ++kf) {
            bf16x8 kfr[4];
#pragma unroll
            for (int nf = 0; nf < 4; ++nf)
                kfr[nf] = *(const bf16x8*)(Kb + (nf * 16 + lr) * 128 + (((kf * 4 + lg) ^ (lr & 7)) * 16));
#pragma unroll
            for (int nf = 0; nf < 4; ++nf)
                s[nf] = __builtin_amdgcn_mfma_f32_16x16x32_bf16(kfr[nf], qf[kf], s[nf], 0, 0, 0);
        }

        const bool needMask = (kv0 + 63 > wq0);
        const int qg = wq0 + lr;
        float mx = -1e30f;
#pragma unroll
        for (int nf = 0; nf < 4; ++nf)
#pragma unroll
            for (int r = 0; r < 4; ++r) {
                float sv = s[nf][r];
                if (needMask) {
                    int kvg = kv0 + nf * 16 + lg * 4 + r;
                    sv = (kvg > qg) ? -1e30f : sv;
                    s[nf][r] = sv;
                }
                mx = fmaxf(mx, sv);
            }
        mx = fmaxf(mx, __shfl_xor(mx, 16, 64));
        mx = fmaxf(mx, __shfl_xor(mx, 32, 64));

        // defer-max (T13): only rescale when max grows by > 8 (exp2 domain)
        bool grow = __any(mx > m_run + 8.0f);
        float sc = 0.0f;
        if (grow) {
            float mnew = fmaxf(m_run, mx);
            sc = __builtin_amdgcn_exp2f(m_run - mnew);
            m_run = mnew;
        }
        float rsum = 0.f;
#pragma unroll
        for (int nf = 0; nf < 4; ++nf)
#pragma unroll
            for (int r = 0; r < 4; ++r) {
                float p = __builtin_amdgcn_exp2f(s[nf][r] - m_run);
                s[nf][r] = p;
                rsum += p;
            }
        rsum += __shfl_xor(rsum, 16, 64);
        rsum += __shfl_xor(rsum, 32, 64);
        if (grow) {
            l_run = l_run * sc + rsum;
#pragma unroll
            for (int r = 0; r < 4; ++r) {
                float sco = __shfl(sc, lg * 4 + r, 64);
#pragma unroll
                for (int df = 0; df < 4; ++df) o[df][r] *= sco;
            }
        } else {
            l_run += rsum;
        }

        // P^T regs -> per-wave LDS as P[q][kv] (packed b64 writes), then PV
        __hip_bfloat16* Pw = &Pl[wave][0];
#pragma unroll
        for (int nf = 0; nf < 4; ++nf) {
            union { __hip_bfloat16 h[4]; uint2 u; } pk;
#pragma unroll
            for (int r = 0; r < 4; ++r) pk.h[r] = __float2bfloat16(s[nf][r]);
            *(uint2*)&Pw[lr * 72 + nf * 16 + lg * 4] = pk.u;
        }

#pragma unroll
        for (int ks = 0; ks < 2; ++ks) {
            bf16x8 pf = *(const bf16x8*)&Pw[lr * 72 + ks * 32 + lg * 8];
            bf16x8 vf[4];
#pragma unroll
            for (int df = 0; df < 4; ++df)
                vf[df] = *(const bf16x8*)(Vb + (df * 16 + lr) * 128 + (((ks * 4 + lg) ^ (lr & 7)) * 16));
#pragma unroll
            for (int df = 0; df < 4; ++df)
                o[df] = __builtin_amdgcn_mfma_f32_16x16x32_bf16(pf, vf[df], o[df], 0, 0, 0);
        }
    }

    // normalize + store att (bf16); l broadcast into O-row layout (row = lg*4+r)
#pragma unroll
    for (int r = 0; r < 4; ++r) {
        float lo = __shfl(l_run, lg * 4 + r, 64);
        float inv = 1.0f / lo;
        int qg = wq0 + lg * 4 + r;
#pragma unroll
        for (int df = 0; df < 4; ++df)
            att[baseQK + (size_t)qg * CC + df * 16 + lr] = __float2bfloat16(o[df][r] * inv);
    }
}

// ---------------------------------------------------------------------------
extern "C" void kernel_launch(void* const* d_in, const int* in_sizes, int n_in,
                              void* d_out, int out_size, void* d_ws, size_t ws_size,
                              hipStream_t stream) {
    const float* x  = (const float*)d_in[0];
    // d_in[1] = attention_mask: no-op in the reference
    const float* Wq = (const float*)d_in[2];
    const float* Wk = (const float*)d_in[3];
    const float* Wv = (const float*)d_in[4];
    const float* Wp = (const float*)d_in[5];
    const float* bp = (const float*)d_in[6];
    float* out = (float*)d_out;

    __hip_bfloat16* ws  = (__hip_bfloat16*)d_ws;
    __hip_bfloat16* xb  = ws;                       // MM*CC
    __hip_bfloat16* wqt = xb  + (size_t)MM * CC;    // CC*CC each, contiguous (QKV concat + Wp)
    __hip_bfloat16* wpt = wqt + 3 * (size_t)CC * CC;
    __hip_bfloat16* Qb  = wpt + (size_t)CC * CC;    // MM*CC
    __hip_bfloat16* Kb  = Qb  + (size_t)MM * CC;    // MM*CC
    __hip_bfloat16* VtG = Kb  + (size_t)MM * CC;    // [B][H][D][T]
    __hip_bfloat16* att = VtG + (size_t)MM * CC;    // MM*CC

    // 1) conversions (fused weight transposes)
    conv_bf16<<<(MM * CC / 4 + 255) / 256, 256, 0, stream>>>(x, xb, MM * CC / 4);
    transpose_conv4<<<dim3(CC / 32, CC / 32, 4), 256, 0, stream>>>(Wq, Wk, Wv, Wp, wqt);

    // 2) fused QKV projection (N=3072; Q pre-scaled; V written per-head transposed)
    dim3 gq(3 * CC / 128, MM / 128);  // (24, 32)
    gemm_bt<1><<<gq, 256, 0, stream>>>(xb, wqt, Qb, Kb, VtG, nullptr, MM, 3 * CC, CC);

    // 3) causal attention (1-D grid, XCD-contiguous mapping, 512-thread blocks)
    attn_kernel<<<dim3(512), 512, 0, stream>>>(Qb, Kb, VtG, att);

    // 4) output projection + bias (fp32 out)
    dim3 gp(CC / 128, MM / 128);  // (8, 32)
    gemm_bt<2><<<gp, 256, 0, stream>>>(att, wpt, out, nullptr, nullptr, bp, MM, CC, CC);
}